// Round 1
// baseline (1949.423 us; speedup 1.0000x reference)
//
#include <hip/hip_runtime.h>

#define NN 262144
#define HH 128
#define EE 16
#define MAXD 12
#define CAP 8192   // per-(depth,category) capacity; expected ~5041, sigma ~70 -> 45 sigma margin

// ---------------------------------------------------------------------------
// init: zero bucket counters (12 depths x 3 cats) and active counters (12 L + 12 H)
__global__ void init_counters(int* cntB, int* cntA) {
    int t = threadIdx.x;
    if (t < 36) cntB[t] = 0;
    if (t < 24) cntA[t] = 0;
}

// ---------------------------------------------------------------------------
// bucket nodes by (depth, state in {0,1,3})
__global__ void bucket_kernel(const int* __restrict__ depths, const int* __restrict__ states,
                              int* cntB, int* listL, int* listR, int* listHd, int n) {
    for (int i = blockIdx.x * blockDim.x + threadIdx.x; i < n; i += gridDim.x * blockDim.x) {
        int d = depths[i];
        if (d < 1) continue;
        int s = states[i];
        int cat = (s == 0) ? 0 : (s == 1) ? 1 : (s == 3) ? 2 : -1;
        if (cat < 0) continue;
        int idx = atomicAdd(&cntB[(d - 1) * 3 + cat], 1);
        if (idx < CAP) {
            int* lst = (cat == 0) ? listL : (cat == 1) ? listR : listHd;
            lst[(d - 1) * CAP + idx] = i;
        }
    }
}

// ---------------------------------------------------------------------------
// mark active parents for this depth (dedupe via depth-tagged flag), allocate
// compact slots, zero the compact accumulation rows.
__global__ void mark_kernel(const int* __restrict__ listL, const int* cntLp,
                            const int* __restrict__ listHd, const int* cntHp,
                            const int* __restrict__ parents,
                            int* flagL, int* slotL, int* activeL, int* cntAL,
                            float* left_c, float* right_c,
                            int* flagH, int* slotH, int* activeH, int* cntAH,
                            float* mh_c, int depth) {
    int nL = *cntLp, nH = *cntHp;
    int total = nL + nH;
    for (int t = blockIdx.x * blockDim.x + threadIdx.x; t < total; t += gridDim.x * blockDim.x) {
        if (t < nL) {
            int p = parents[listL[t]];
            int old = atomicExch(&flagL[p], depth);
            if (old != depth) {
                int s = atomicAdd(cntAL, 1);
                slotL[p] = s;
                activeL[s] = p;
                float4 z = make_float4(0.f, 0.f, 0.f, 0.f);
                float4* a = (float4*)(left_c + (size_t)s * HH);
                float4* b = (float4*)(right_c + (size_t)s * HH);
                #pragma unroll
                for (int q = 0; q < HH / 4; ++q) { a[q] = z; b[q] = z; }
            }
        } else {
            int p = parents[listHd[t - nL]];
            int old = atomicExch(&flagH[p], depth);
            if (old != depth) {
                int s = atomicAdd(cntAH, 1);
                slotH[p] = s;
                activeH[s] = p;
                float4 z = make_float4(0.f, 0.f, 0.f, 0.f);
                float4* a = (float4*)(mh_c + (size_t)s * HH);
                #pragma unroll
                for (int q = 0; q < HH / 4; ++q) a[q] = z;
            }
        }
    }
}

// ---------------------------------------------------------------------------
// scatter-add x of left/right children into compact parent rows
__global__ void scatter_kernel(const int* __restrict__ listL, const int* cntLp,
                               const int* __restrict__ listR, const int* cntRp,
                               const int* __restrict__ parents,
                               const int* __restrict__ flagL, const int* __restrict__ slotL,
                               const float* __restrict__ x,
                               float* left_c, float* right_c, int depth) {
    int nL = *cntLp, nR = *cntRp;
    int total = (nL + nR) * (HH / 4);
    for (int t = blockIdx.x * blockDim.x + threadIdx.x; t < total; t += gridDim.x * blockDim.x) {
        int e = t >> 5;          // / (HH/4) == /32
        int q = t & 31;
        int child;
        float* dst;
        if (e < nL) {
            child = listL[e];
            int p = parents[child];
            dst = left_c + (size_t)slotL[p] * HH;
        } else {
            child = listR[e - nL];
            int p = parents[child];
            if (flagL[p] != depth) continue;   // parent has no left child -> x_parents never applied
            dst = right_c + (size_t)slotL[p] * HH;
        }
        float4 v = ((const float4*)(x + (size_t)child * HH))[q];
        atomicAdd(dst + q * 4 + 0, v.x);
        atomicAdd(dst + q * 4 + 1, v.y);
        atomicAdd(dst + q * 4 + 2, v.z);
        atomicAdd(dst + q * 4 + 3, v.w);
    }
}

// ---------------------------------------------------------------------------
// generic 2-layer MLP over compact rows; 8 rows / block, 128 threads.
// MODE 0 (merger): rows=activeL slots; in=[left_c, right_c, pef[p]];  out=xpar_c[slot]
// MODE 1 (lep):    rows=listH children; in=[x[child], plef[child]];   out=atomicAdd mh_c[slotH[parent]]
// MODE 2 (lem):    rows=activeH slots; in=[x[p], mh_c[slot]];         out=xmrg_c[slot]
template <int MODE, int INDIM>
__global__ __launch_bounds__(128)
void mlp_kernel(const int* __restrict__ rowList, const int* cntPtr,
                const int* __restrict__ parents, const int* __restrict__ slotH,
                const float* __restrict__ src0, const float* __restrict__ src1,
                const float* __restrict__ src2,
                const float* __restrict__ W1, const float* __restrict__ b1,
                const float* __restrict__ W2, const float* __restrict__ b2,
                float* __restrict__ out) {
    __shared__ float sh_in[8][INDIM];
    __shared__ float sh_h[8][HH];
    int n = *cntPtr;
    int rowBase = blockIdx.x * 8;
    if (rowBase >= n) return;
    int tid = threadIdx.x;

    for (int idx = tid; idx < 8 * INDIM; idx += 128) {
        int r = idx / INDIM;
        int k = idx - r * INDIM;
        int g = rowBase + r;
        float v = 0.f;
        if (g < n) {
            if (MODE == 0) {
                if (k < HH)            v = src0[(size_t)g * HH + k];
                else if (k < 2 * HH)   v = src1[(size_t)g * HH + (k - HH)];
                else                   v = src2[(size_t)rowList[g] * EE + (k - 2 * HH)];
            } else if (MODE == 1) {
                int child = rowList[g];
                v = (k < HH) ? src0[(size_t)child * HH + k]
                             : src1[(size_t)child * EE + (k - HH)];
            } else {
                v = (k < HH) ? src0[(size_t)rowList[g] * HH + k]
                             : src1[(size_t)g * HH + (k - HH)];
            }
        }
        sh_in[r][k] = v;
    }
    __syncthreads();

    int j = tid;
    float acc[8];
    float bb = b1[j];
    #pragma unroll
    for (int r = 0; r < 8; ++r) acc[r] = bb;
    for (int k = 0; k < INDIM; ++k) {
        float wv = W1[k * HH + j];
        #pragma unroll
        for (int r = 0; r < 8; ++r) acc[r] += sh_in[r][k] * wv;
    }
    #pragma unroll
    for (int r = 0; r < 8; ++r) sh_h[r][j] = fmaxf(acc[r], 0.f);
    __syncthreads();

    float bb2 = b2[j];
    float acc2[8];
    #pragma unroll
    for (int r = 0; r < 8; ++r) acc2[r] = bb2;
    for (int k = 0; k < HH; ++k) {
        float wv = W2[k * HH + j];
        #pragma unroll
        for (int r = 0; r < 8; ++r) acc2[r] += sh_h[r][k] * wv;
    }

    for (int r = 0; r < 8; ++r) {
        int g = rowBase + r;
        if (g >= n) break;
        if (MODE == 1) {
            int child = rowList[g];
            atomicAdd(&out[(size_t)slotH[parents[child]] * HH + j], acc2[r]);
        } else {
            out[(size_t)g * HH + j] = acc2[r];
        }
    }
}

// ---------------------------------------------------------------------------
// write staged outputs into x: x_parents wins over x_merged
__global__ void apply_kernel(const int* __restrict__ activeL, const int* cntALp,
                             const int* __restrict__ activeH, const int* cntAHp,
                             const int* __restrict__ flagL,
                             const float* __restrict__ xpar_c, const float* __restrict__ xmrg_c,
                             float* __restrict__ x, int depth) {
    int nL = *cntALp, nH = *cntAHp;
    int total = (nL + nH) * (HH / 4);
    for (int t = blockIdx.x * blockDim.x + threadIdx.x; t < total; t += gridDim.x * blockDim.x) {
        int e = t >> 5;
        int q = t & 31;
        int p;
        const float* src;
        if (e < nL) {
            p = activeL[e];
            src = xpar_c + (size_t)e * HH;
        } else {
            int e2 = e - nL;
            p = activeH[e2];
            if (flagL[p] == depth) continue;   // parents_mask takes priority
            src = xmrg_c + (size_t)e2 * HH;
        }
        ((float4*)(x + (size_t)p * HH))[q] = ((const float4*)src)[q];
    }
}

// ---------------------------------------------------------------------------
extern "C" void kernel_launch(void* const* d_in, const int* in_sizes, int n_in,
                              void* d_out, int out_size, void* d_ws, size_t ws_size,
                              hipStream_t stream) {
    const float* x_in   = (const float*)d_in[0];
    const int*   edge   = (const int*)d_in[1];
    const int*   depths = (const int*)d_in[2];
    const int*   states = (const int*)d_in[3];
    const float* pef    = (const float*)d_in[4];
    const float* plef   = (const float*)d_in[5];
    const float* mW1 = (const float*)d_in[6];
    const float* mb1 = (const float*)d_in[7];
    const float* mW2 = (const float*)d_in[8];
    const float* mb2 = (const float*)d_in[9];
    const float* pW1 = (const float*)d_in[10];
    const float* pb1 = (const float*)d_in[11];
    const float* pW2 = (const float*)d_in[12];
    const float* pb2 = (const float*)d_in[13];
    const float* eW1 = (const float*)d_in[14];
    const float* eb1 = (const float*)d_in[15];
    const float* eW2 = (const float*)d_in[16];
    const float* eb2 = (const float*)d_in[17];

    float* x = (float*)d_out;                 // working x lives in d_out
    const int* parents = edge + NN;           // edge_index[1]

    char* w = (char*)d_ws;
    auto alloc = [&](size_t bytes) {
        void* p = (void*)w;
        w += (bytes + 255) & ~(size_t)255;
        return p;
    };
    int* cntB    = (int*)alloc(36 * 4);
    int* cntA    = (int*)alloc(24 * 4);            // [0..11]=L, [12..23]=H
    int* flagL   = (int*)alloc((size_t)NN * 4);
    int* flagH   = (int*)alloc((size_t)NN * 4);
    int* slotL   = (int*)alloc((size_t)NN * 4);
    int* slotH   = (int*)alloc((size_t)NN * 4);
    int* listL   = (int*)alloc((size_t)12 * CAP * 4);
    int* listR   = (int*)alloc((size_t)12 * CAP * 4);
    int* listHd  = (int*)alloc((size_t)12 * CAP * 4);
    int* activeL = (int*)alloc((size_t)CAP * 4);
    int* activeH = (int*)alloc((size_t)CAP * 4);
    float* left_c  = (float*)alloc((size_t)CAP * HH * 4);
    float* right_c = (float*)alloc((size_t)CAP * HH * 4);
    float* mh_c    = (float*)alloc((size_t)CAP * HH * 4);
    float* xpar_c  = (float*)alloc((size_t)CAP * HH * 4);
    float* xmrg_c  = (float*)alloc((size_t)CAP * HH * 4);

    hipMemsetAsync(flagL, 0xFF, (size_t)NN * 4, stream);
    hipMemsetAsync(flagH, 0xFF, (size_t)NN * 4, stream);
    init_counters<<<1, 64, 0, stream>>>(cntB, cntA);
    hipMemcpyAsync(x, x_in, (size_t)NN * HH * 4, hipMemcpyDeviceToDevice, stream);
    bucket_kernel<<<1024, 256, 0, stream>>>(depths, states, cntB, listL, listR, listHd, NN);

    for (int d = MAXD; d >= 1; --d) {
        int bi = d - 1;
        const int* cl = cntB + bi * 3;
        mark_kernel<<<128, 256, 0, stream>>>(listL + (size_t)bi * CAP, cl + 0,
                                             listHd + (size_t)bi * CAP, cl + 2, parents,
                                             flagL, slotL, activeL, cntA + bi, left_c, right_c,
                                             flagH, slotH, activeH, cntA + 12 + bi, mh_c, d);
        scatter_kernel<<<1024, 256, 0, stream>>>(listL + (size_t)bi * CAP, cl + 0,
                                                 listR + (size_t)bi * CAP, cl + 1, parents,
                                                 flagL, slotL, x, left_c, right_c, d);
        mlp_kernel<0, 2 * HH + EE><<<CAP / 8, 128, 0, stream>>>(
            activeL, cntA + bi, parents, nullptr,
            left_c, right_c, pef, mW1, mb1, mW2, mb2, xpar_c);
        mlp_kernel<1, HH + EE><<<CAP / 8, 128, 0, stream>>>(
            listHd + (size_t)bi * CAP, cl + 2, parents, slotH,
            x, plef, nullptr, pW1, pb1, pW2, pb2, mh_c);
        mlp_kernel<2, 2 * HH><<<CAP / 8, 128, 0, stream>>>(
            activeH, cntA + 12 + bi, parents, nullptr,
            x, mh_c, nullptr, eW1, eb1, eW2, eb2, xmrg_c);
        apply_kernel<<<1024, 256, 0, stream>>>(activeL, cntA + bi, activeH, cntA + 12 + bi,
                                               flagL, xpar_c, xmrg_c, x, d);
    }
}

// Round 2
// 1060.452 us; speedup vs baseline: 1.8383x; 1.8383x over previous
//
#include <hip/hip_runtime.h>

#define NN 262144
#define HH 128
#define EE 16
#define MAXD 12
#define CAP 8192          // per-(depth,category) capacity; expected ~5041
#define NB_MLP (CAP / 8)  // 1024 blocks of 8 rows
#define NB_SC 256         // scatter blocks appended to fused kernel

// ---------------------------------------------------------------------------
__global__ void init_counters(int* cntB, int* cntA) {
    int t = threadIdx.x;
    if (t < 36) cntB[t] = 0;
    if (t < 24) cntA[t] = 0;
}

// ---------------------------------------------------------------------------
// bucket nodes by (depth, state in {0,1,3}) — two-level atomics:
// LDS rank within block, one global atomicAdd per (block,bucket).
__global__ __launch_bounds__(1024)
void bucket_kernel(const int* __restrict__ depths, const int* __restrict__ states,
                   int* cntB, int* listL, int* listR, int* listHd, int n) {
    __shared__ int lcnt[36], lbase[36];
    int tid = threadIdx.x;
    if (tid < 36) lcnt[tid] = 0;
    __syncthreads();
    int i = blockIdx.x * 1024 + tid;
    int b = -1, rank = 0;
    if (i < n) {
        int d = depths[i], s = states[i];
        if (d >= 1 && (s == 0 || s == 1 || s == 3)) {
            int cat = (s == 3) ? 2 : s;
            b = (d - 1) * 3 + cat;
            rank = atomicAdd(&lcnt[b], 1);
        }
    }
    __syncthreads();
    if (tid < 36 && lcnt[tid] > 0) lbase[tid] = atomicAdd(&cntB[tid], lcnt[tid]);
    __syncthreads();
    if (b >= 0) {
        int idx = lbase[b] + rank;
        if (idx < CAP) {
            int dd = b / 3, cat = b - dd * 3;
            int* lst = (cat == 0) ? listL : (cat == 1) ? listR : listHd;
            lst[dd * CAP + idx] = i;
        }
    }
}

// ---------------------------------------------------------------------------
// mark active parents (dedupe via depth-tagged flag), two-level slot alloc,
// zero the compact accumulation rows.
__global__ __launch_bounds__(256)
void mark_kernel(const int* __restrict__ listL, const int* cntLp,
                 const int* __restrict__ listHd, const int* cntHp,
                 const int* __restrict__ parents,
                 int* flagL, int* slotL, int* activeL, int* cntAL,
                 float* left_c, float* right_c,
                 int* flagH, int* slotH, int* activeH, int* cntAH,
                 float* mh_c, int depth) {
    __shared__ int lc[2], lb[2];
    int tid = threadIdx.x;
    int nL = min(*cntLp, CAP), nH = min(*cntHp, CAP);
    if (tid < 2) lc[tid] = 0;
    __syncthreads();
    int t = blockIdx.x * 256 + tid;
    int p = -1, which = 0, rank = 0;
    if (t < nL + nH) {
        which = (t >= nL) ? 1 : 0;
        p = which ? parents[listHd[t - nL]] : parents[listL[t]];
        int* flag = which ? flagH : flagL;
        int old = atomicExch(&flag[p], depth);
        if (old != depth) rank = atomicAdd(&lc[which], 1);
        else p = -1;
    }
    __syncthreads();
    if (tid < 2 && lc[tid] > 0) lb[tid] = atomicAdd(tid ? cntAH : cntAL, lc[tid]);
    __syncthreads();
    if (p >= 0) {
        int s = lb[which] + rank;
        float4 z = make_float4(0.f, 0.f, 0.f, 0.f);
        if (which) {
            slotH[p] = s; activeH[s] = p;
            float4* a = (float4*)(mh_c + (size_t)s * HH);
            #pragma unroll
            for (int q = 0; q < HH / 4; ++q) a[q] = z;
        } else {
            slotL[p] = s; activeL[s] = p;
            float4* a = (float4*)(left_c + (size_t)s * HH);
            float4* b2 = (float4*)(right_c + (size_t)s * HH);
            #pragma unroll
            for (int q = 0; q < HH / 4; ++q) { a[q] = z; b2[q] = z; }
        }
    }
}

// ---------------------------------------------------------------------------
// 2-layer MLP core: 256 threads, 8 rows/block, split-K across 2 half-groups.
// MODE 0 (merger): rows=activeL slots; in=[left_c,right_c,pef[p]]; writes x[p] directly
// MODE 1 (lep):    rows=listHd children; in=[x[c],plef[c]]; atomicAdd mh_c[slotH[parent]]
// MODE 2 (lem):    rows=activeH slots; in=[x[p],mh_c]; writes x[p] if flagL[p]!=depth
template <int MODE, int INDIM>
__device__ __forceinline__
void mlp_core(int mblk, int tid,
              const int* __restrict__ rowList, const int* __restrict__ cntPtr,
              const int* __restrict__ parents, const int* __restrict__ slotH,
              const int* __restrict__ flagL, int depth,
              const float* __restrict__ src0, const float* __restrict__ src1,
              const float* __restrict__ src2,
              const float* __restrict__ W1, const float* __restrict__ b1,
              const float* __restrict__ W2, const float* __restrict__ b2,
              float* __restrict__ out, float* sh_raw) {
    const int n = min(*cntPtr, CAP);
    const int rowBase = mblk * 8;
    if (rowBase >= n) return;
    float (*sh_in)[INDIM] = (float (*)[INDIM])sh_raw;
    float (*sh_h)[HH]     = (float (*)[HH])(sh_raw + 8 * INDIM);
    float (*sh_pt)[HH]    = (float (*)[HH])(sh_raw + 8 * INDIM + 8 * HH);

    for (int idx = tid; idx < 8 * INDIM; idx += 256) {
        int r = idx / INDIM, k = idx - r * INDIM;
        int g = rowBase + r;
        float v = 0.f;
        if (g < n) {
            if (MODE == 0) {
                v = (k < HH)     ? src0[(size_t)g * HH + k]
                  : (k < 2 * HH) ? src1[(size_t)g * HH + (k - HH)]
                                 : src2[(size_t)rowList[g] * EE + (k - 2 * HH)];
            } else if (MODE == 1) {
                int c = rowList[g];
                v = (k < HH) ? src0[(size_t)c * HH + k]
                             : src1[(size_t)c * EE + (k - HH)];
            } else {
                v = (k < HH) ? src0[(size_t)rowList[g] * HH + k]
                             : src1[(size_t)g * HH + (k - HH)];
            }
        }
        sh_in[r][k] = v;
    }
    __syncthreads();

    const int h = tid >> 7, j = tid & 127;
    constexpr int KH1 = INDIM / 2;
    float acc[8];
    #pragma unroll
    for (int r = 0; r < 8; ++r) acc[r] = 0.f;
    {
        const float* Wp = W1 + (size_t)h * KH1 * HH + j;
        for (int k = 0; k < KH1; k += 8) {
            float wv[8];
            #pragma unroll
            for (int u = 0; u < 8; ++u) wv[u] = Wp[(size_t)(k + u) * HH];
            #pragma unroll
            for (int u = 0; u < 8; ++u) {
                float w = wv[u];
                int kk = h * KH1 + k + u;
                #pragma unroll
                for (int r = 0; r < 8; ++r) acc[r] += sh_in[r][kk] * w;
            }
        }
    }
    if (h == 1) {
        #pragma unroll
        for (int r = 0; r < 8; ++r) sh_pt[r][j] = acc[r];
    }
    __syncthreads();
    if (h == 0) {
        float bb = b1[j];
        #pragma unroll
        for (int r = 0; r < 8; ++r) sh_h[r][j] = fmaxf(acc[r] + sh_pt[r][j] + bb, 0.f);
    }
    __syncthreads();

    float acc2[8];
    #pragma unroll
    for (int r = 0; r < 8; ++r) acc2[r] = 0.f;
    {
        const float* Wp = W2 + (size_t)h * (HH / 2) * HH + j;
        for (int k = 0; k < HH / 2; k += 8) {
            float wv[8];
            #pragma unroll
            for (int u = 0; u < 8; ++u) wv[u] = Wp[(size_t)(k + u) * HH];
            #pragma unroll
            for (int u = 0; u < 8; ++u) {
                float w = wv[u];
                int kk = h * (HH / 2) + k + u;
                #pragma unroll
                for (int r = 0; r < 8; ++r) acc2[r] += sh_h[r][kk] * w;
            }
        }
    }
    if (h == 1) {
        #pragma unroll
        for (int r = 0; r < 8; ++r) sh_pt[r][j] = acc2[r];
    }
    __syncthreads();
    if (h == 0) {
        float bb2 = b2[j];
        for (int r = 0; r < 8; ++r) {
            int g = rowBase + r;
            if (g >= n) break;
            float val = acc2[r] + sh_pt[r][j] + bb2;
            if (MODE == 1) {
                atomicAdd(&out[(size_t)slotH[parents[rowList[g]]] * HH + j], val);
            } else if (MODE == 0) {
                out[(size_t)rowList[g] * HH + j] = val;       // x[p] = x_parents
            } else {
                int p = rowList[g];
                if (flagL[p] != depth)                         // parents_mask priority
                    out[(size_t)p * HH + j] = val;             // x[p] = x_merged
            }
        }
    }
}

// ---------------------------------------------------------------------------
// fused: blocks [0,NB_MLP) run lep MLP; blocks [NB_MLP, NB_MLP+NB_SC) run the
// left/right scatter-add. Both only READ x — safe to co-schedule.
__global__ __launch_bounds__(256)
void scatter_lep_kernel(const int* __restrict__ listL, const int* cntLp,
                        const int* __restrict__ listR, const int* cntRp,
                        const int* __restrict__ listHd, const int* cntHp,
                        const int* __restrict__ parents,
                        const int* __restrict__ flagL, const int* __restrict__ slotL,
                        const int* __restrict__ slotH,
                        const float* __restrict__ x,
                        float* left_c, float* right_c,
                        const float* __restrict__ plef,
                        const float* __restrict__ pW1, const float* __restrict__ pb1,
                        const float* __restrict__ pW2, const float* __restrict__ pb2,
                        float* mh_c, int depth) {
    __shared__ float sh_raw[8 * (HH + EE) + 16 * HH];
    if (blockIdx.x < NB_MLP) {
        mlp_core<1, HH + EE>(blockIdx.x, threadIdx.x, listHd, cntHp, parents, slotH,
                             nullptr, depth, x, plef, nullptr,
                             pW1, pb1, pW2, pb2, mh_c, sh_raw);
    } else {
        int nL = min(*cntLp, CAP), nR = min(*cntRp, CAP);
        int total = (nL + nR) * (HH / 4);
        for (int t = (blockIdx.x - NB_MLP) * 256 + threadIdx.x; t < total;
             t += NB_SC * 256) {
            int e = t >> 5, q = t & 31;
            int child;
            float* dst;
            if (e < nL) {
                child = listL[e];
                dst = left_c + (size_t)slotL[parents[child]] * HH;
            } else {
                child = listR[e - nL];
                int p = parents[child];
                if (flagL[p] != depth) continue;  // parent w/o left child: never applied
                dst = right_c + (size_t)slotL[p] * HH;
            }
            float4 v = ((const float4*)(x + (size_t)child * HH))[q];
            atomicAdd(dst + q * 4 + 0, v.x);
            atomicAdd(dst + q * 4 + 1, v.y);
            atomicAdd(dst + q * 4 + 2, v.z);
            atomicAdd(dst + q * 4 + 3, v.w);
        }
    }
}

// ---------------------------------------------------------------------------
template <int MODE, int INDIM>
__global__ __launch_bounds__(256)
void mlp_kernel(const int* __restrict__ rowList, const int* __restrict__ cntPtr,
                const int* __restrict__ parents, const int* __restrict__ slotH,
                const int* __restrict__ flagL, int depth,
                const float* __restrict__ src0, const float* __restrict__ src1,
                const float* __restrict__ src2,
                const float* __restrict__ W1, const float* __restrict__ b1,
                const float* __restrict__ W2, const float* __restrict__ b2,
                float* __restrict__ out) {
    __shared__ float sh_raw[8 * INDIM + 16 * HH];
    mlp_core<MODE, INDIM>(blockIdx.x, threadIdx.x, rowList, cntPtr, parents, slotH,
                          flagL, depth, src0, src1, src2, W1, b1, W2, b2, out, sh_raw);
}

// ---------------------------------------------------------------------------
extern "C" void kernel_launch(void* const* d_in, const int* in_sizes, int n_in,
                              void* d_out, int out_size, void* d_ws, size_t ws_size,
                              hipStream_t stream) {
    const float* x_in   = (const float*)d_in[0];
    const int*   edge   = (const int*)d_in[1];
    const int*   depths = (const int*)d_in[2];
    const int*   states = (const int*)d_in[3];
    const float* pef    = (const float*)d_in[4];
    const float* plef   = (const float*)d_in[5];
    const float* mW1 = (const float*)d_in[6];
    const float* mb1 = (const float*)d_in[7];
    const float* mW2 = (const float*)d_in[8];
    const float* mb2 = (const float*)d_in[9];
    const float* pW1 = (const float*)d_in[10];
    const float* pb1 = (const float*)d_in[11];
    const float* pW2 = (const float*)d_in[12];
    const float* pb2 = (const float*)d_in[13];
    const float* eW1 = (const float*)d_in[14];
    const float* eb1 = (const float*)d_in[15];
    const float* eW2 = (const float*)d_in[16];
    const float* eb2 = (const float*)d_in[17];

    float* x = (float*)d_out;
    const int* parents = edge + NN;

    char* w = (char*)d_ws;
    auto alloc = [&](size_t bytes) {
        void* p = (void*)w;
        w += (bytes + 255) & ~(size_t)255;
        return p;
    };
    int* cntB    = (int*)alloc(36 * 4);
    int* cntA    = (int*)alloc(24 * 4);   // [0..11]=L, [12..23]=H
    int* flagL   = (int*)alloc((size_t)NN * 4);
    int* flagH   = (int*)alloc((size_t)NN * 4);
    int* slotL   = (int*)alloc((size_t)NN * 4);
    int* slotH   = (int*)alloc((size_t)NN * 4);
    int* listL   = (int*)alloc((size_t)12 * CAP * 4);
    int* listR   = (int*)alloc((size_t)12 * CAP * 4);
    int* listHd  = (int*)alloc((size_t)12 * CAP * 4);
    int* activeL = (int*)alloc((size_t)CAP * 4);
    int* activeH = (int*)alloc((size_t)CAP * 4);
    float* left_c  = (float*)alloc((size_t)CAP * HH * 4);
    float* right_c = (float*)alloc((size_t)CAP * HH * 4);
    float* mh_c    = (float*)alloc((size_t)CAP * HH * 4);

    hipMemsetAsync(flagL, 0xFF, (size_t)NN * 4, stream);
    hipMemsetAsync(flagH, 0xFF, (size_t)NN * 4, stream);
    init_counters<<<1, 64, 0, stream>>>(cntB, cntA);
    hipMemcpyAsync(x, x_in, (size_t)NN * HH * 4, hipMemcpyDeviceToDevice, stream);
    bucket_kernel<<<NN / 1024, 1024, 0, stream>>>(depths, states, cntB,
                                                  listL, listR, listHd, NN);

    for (int d = MAXD; d >= 1; --d) {
        int bi = d - 1;
        const int* cl = cntB + bi * 3;
        mark_kernel<<<2 * CAP / 256, 256, 0, stream>>>(
            listL + (size_t)bi * CAP, cl + 0,
            listHd + (size_t)bi * CAP, cl + 2, parents,
            flagL, slotL, activeL, cntA + bi, left_c, right_c,
            flagH, slotH, activeH, cntA + 12 + bi, mh_c, d);
        scatter_lep_kernel<<<NB_MLP + NB_SC, 256, 0, stream>>>(
            listL + (size_t)bi * CAP, cl + 0,
            listR + (size_t)bi * CAP, cl + 1,
            listHd + (size_t)bi * CAP, cl + 2,
            parents, flagL, slotL, slotH, x, left_c, right_c,
            plef, pW1, pb1, pW2, pb2, mh_c, d);
        // merger: writes x[p] directly (rows lem might also read are exactly the
        // rows whose lem output is discarded by the flagL priority check)
        mlp_kernel<0, 2 * HH + EE><<<NB_MLP, 256, 0, stream>>>(
            activeL, cntA + bi, parents, nullptr, flagL, d,
            left_c, right_c, pef, mW1, mb1, mW2, mb2, x);
        // lem: writes x[p] directly where flagL[p] != d
        mlp_kernel<2, 2 * HH><<<NB_MLP, 256, 0, stream>>>(
            activeH, cntA + 12 + bi, parents, nullptr, flagL, d,
            x, mh_c, nullptr, eW1, eb1, eW2, eb2, x);
    }
}